// Round 13
// baseline (3491.437 us; speedup 1.0000x reference)
//
#include <hip/hip_runtime.h>

__device__ __forceinline__ int swz(int c){ return c + ((c>>5)<<2); }  // bank swizzle

// ---------------------------------------------------------------- encoder
__global__ __launch_bounds__(256) void encoder_kernel(
    const float* __restrict__ xc, const float* __restrict__ yc, const float* __restrict__ xt,
    const float* __restrict__ W1, const float* __restrict__ b1,
    const float* __restrict__ W2, const float* __restrict__ b2,
    float* __restrict__ z)
{
  __shared__ float zin[10];
  __shared__ float hid[256];
  int blk = blockIdx.x; int b = blk>>10; int t = blk & 1023;
  int tid = threadIdx.x;
  if (tid < 10){
    float v;
    if (tid < 8)      v = (t<512) ? xc[((size_t)b*512+t)*8+tid] : xt[((size_t)b*512+(t-512))*8+tid];
    else if (tid==8)  v = (t<512) ? yc[(size_t)b*512+t] : 0.f;
    else              v = (t<512) ? 0.f : 1.f;
    zin[tid]=v;
  }
  __syncthreads();
  float s = b1[tid];
  #pragma unroll
  for (int i=0;i<10;i++) s += zin[i]*W1[i*256+tid];
  hid[tid] = fmaxf(s, 0.f);
  __syncthreads();
  float o = b2[tid];
  for (int j=0;j<256;j++) o += hid[j]*W2[j*256+tid];
  z[((size_t)b*1024+t)*256 + tid] = o;
}

// ---------------------------------------------------------------- layernorm
__global__ __launch_bounds__(256) void ln_fast(const float* __restrict__ z,
    const float* __restrict__ g, const float* __restrict__ be, float* __restrict__ h)
{
  __shared__ float red[256];
  int row = blockIdx.x, tid = threadIdx.x;
  float x = z[(size_t)row*256 + tid];
  red[tid] = x; __syncthreads();
  for (int s=128; s>0; s>>=1){ if (tid<s) red[tid]+=red[tid+s]; __syncthreads(); }
  float mu = red[0] * (1.f/256.f); __syncthreads();
  float d = x - mu;
  red[tid] = d*d; __syncthreads();
  for (int s=128; s>0; s>>=1){ if (tid<s) red[tid]+=red[tid+s]; __syncthreads(); }
  float var = red[0] * (1.f/256.f);
  float r = rsqrtf(var + 1e-5f);
  h[(size_t)row*256+tid] = d*r*g[tid] + be[tid];
}

// ------------------------------------------------- GEMM 128x128, 8x8 micro
// out[M x N] = EPI(A[M x K] @ B[K x N] + bias); EPI 0 plain, 1 relu, 2 +resid
template<int EPI>
__global__ __launch_bounds__(256) void gemm_big(
    const float* __restrict__ A, const float* __restrict__ B,
    const float* __restrict__ bias, const float* __restrict__ resid,
    float* __restrict__ out, int N, int K)
{
  __shared__ float As[16][140];   // [k][swz(m)]
  __shared__ float Bs[16][140];   // [k][swz(n)]
  const int tid = threadIdx.x;
  const int tx = tid & 15, ty = tid >> 4;
  const int m0 = blockIdx.y*128, n0 = blockIdx.x*128;
  const int am = tid >> 1, ak = (tid & 1) * 8;
  const int bk = tid >> 4, bn = (tid & 15) * 8;
  float acc[8][8] = {};
  for (int kk = 0; kk < K; kk += 16){
    float4 av0 = *(const float4*)&A[(size_t)(m0+am)*K + kk + ak];
    float4 av1 = *(const float4*)&A[(size_t)(m0+am)*K + kk + ak + 4];
    float4 bv0 = *(const float4*)&B[(size_t)(kk+bk)*N + n0 + bn];
    float4 bv1 = *(const float4*)&B[(size_t)(kk+bk)*N + n0 + bn + 4];
    __syncthreads();
    int ams = swz(am);
    As[ak+0][ams]=av0.x; As[ak+1][ams]=av0.y; As[ak+2][ams]=av0.z; As[ak+3][ams]=av0.w;
    As[ak+4][ams]=av1.x; As[ak+5][ams]=av1.y; As[ak+6][ams]=av1.z; As[ak+7][ams]=av1.w;
    *(float4*)&Bs[bk][swz(bn)]   = bv0;
    *(float4*)&Bs[bk][swz(bn+4)] = bv1;
    __syncthreads();
    #pragma unroll
    for (int k=0;k<16;k++){
      float a[8], b[8];
      *(float4*)&a[0] = *(const float4*)&As[k][swz(ty*8)];
      *(float4*)&a[4] = *(const float4*)&As[k][swz(ty*8+4)];
      *(float4*)&b[0] = *(const float4*)&Bs[k][swz(tx*8)];
      *(float4*)&b[4] = *(const float4*)&Bs[k][swz(tx*8+4)];
      #pragma unroll
      for (int i=0;i<8;i++)
        #pragma unroll
        for (int j=0;j<8;j++)
          acc[i][j] += a[i]*b[j];
    }
  }
  const int gc0 = n0 + tx*8;
  float bb[8];
  *(float4*)&bb[0] = *(const float4*)&bias[gc0];
  *(float4*)&bb[4] = *(const float4*)&bias[gc0+4];
  #pragma unroll
  for (int i=0;i<8;i++){
    int gr = m0 + ty*8 + i;
    size_t off = (size_t)gr*N + gc0;
    float v[8];
    #pragma unroll
    for (int j=0;j<8;j++){
      v[j] = acc[i][j] + bb[j];
      if (EPI==1) v[j] = fmaxf(v[j], 0.f);
    }
    if (EPI==2){
      float rv[8];
      *(float4*)&rv[0] = *(const float4*)&resid[off];
      *(float4*)&rv[4] = *(const float4*)&resid[off+4];
      #pragma unroll
      for (int j=0;j<8;j++) v[j] += rv[j];
    }
    *(float4*)&out[off]   = *(float4*)&v[0];
    *(float4*)&out[off+4] = *(float4*)&v[4];
  }
}

// ------------------------------------------------- GEMM 64x128, 4x8 micro (N=256)
template<int EPI>
__global__ __launch_bounds__(256) void gemm_mid(
    const float* __restrict__ A, const float* __restrict__ B,
    const float* __restrict__ bias, const float* __restrict__ resid,
    float* __restrict__ out, int N, int K)
{
  __shared__ float As[16][68];
  __shared__ float Bs[16][140];
  const int tid = threadIdx.x;
  const int tx = tid & 15, ty = tid >> 4;
  const int m0 = blockIdx.y*64, n0 = blockIdx.x*128;
  const int am = tid >> 2, ak = (tid & 3) * 4;
  const int bk = tid >> 4, bn = (tid & 15) * 8;
  float acc[4][8] = {};
  for (int kk = 0; kk < K; kk += 16){
    float4 av = *(const float4*)&A[(size_t)(m0+am)*K + kk + ak];
    float4 bv0 = *(const float4*)&B[(size_t)(kk+bk)*N + n0 + bn];
    float4 bv1 = *(const float4*)&B[(size_t)(kk+bk)*N + n0 + bn + 4];
    __syncthreads();
    As[ak+0][am]=av.x; As[ak+1][am]=av.y; As[ak+2][am]=av.z; As[ak+3][am]=av.w;
    *(float4*)&Bs[bk][swz(bn)]   = bv0;
    *(float4*)&Bs[bk][swz(bn+4)] = bv1;
    __syncthreads();
    #pragma unroll
    for (int k=0;k<16;k++){
      float a[4], b[8];
      *(float4*)&a[0] = *(const float4*)&As[k][ty*4];
      *(float4*)&b[0] = *(const float4*)&Bs[k][swz(tx*8)];
      *(float4*)&b[4] = *(const float4*)&Bs[k][swz(tx*8+4)];
      #pragma unroll
      for (int i=0;i<4;i++)
        #pragma unroll
        for (int j=0;j<8;j++)
          acc[i][j] += a[i]*b[j];
    }
  }
  const int gc0 = n0 + tx*8;
  float bb[8];
  *(float4*)&bb[0] = *(const float4*)&bias[gc0];
  *(float4*)&bb[4] = *(const float4*)&bias[gc0+4];
  #pragma unroll
  for (int i=0;i<4;i++){
    int gr = m0 + ty*4 + i;
    size_t off = (size_t)gr*N + gc0;
    float v[8];
    #pragma unroll
    for (int j=0;j<8;j++){
      v[j] = acc[i][j] + bb[j];
      if (EPI==1) v[j] = fmaxf(v[j], 0.f);
    }
    if (EPI==2){
      float rv[8];
      *(float4*)&rv[0] = *(const float4*)&resid[off];
      *(float4*)&rv[4] = *(const float4*)&resid[off+4];
      #pragma unroll
      for (int j=0;j<8;j++) v[j] += rv[j];
    }
    *(float4*)&out[off]   = *(float4*)&v[0];
    *(float4*)&out[off+4] = *(float4*)&v[4];
  }
}

// ---------------------------------------------------------------- attention v3
// 256 threads: half 0 -> keys 0..255, half 1 -> keys 256..511; online softmax,
// unroll x8, merge via LDS. Target rows (qc>=4, block-uniform) self-attend.
__global__ __launch_bounds__(256) void attn_v3(
    const float* __restrict__ qkv, float* __restrict__ o)
{
  __shared__ float mrg[128][33];   // 33 coprime w/ 32 banks
  const int tid = threadIdx.x;
  const int half = tid >> 7, lq = tid & 127;
  const int qc = blockIdx.x, h = blockIdx.y, b = blockIdx.z;
  const float* base = qkv + (size_t)b*1024*768;
  const int q = qc*128 + lq;
  const float sc = 0.17677669529663687f;   // 1/sqrt(32)
  float Q[32];
  {
    const float4* qp = (const float4*)&base[(size_t)q*768 + h*32];
    #pragma unroll
    for (int p=0;p<8;p++){
      float4 t = qp[p];
      Q[p*4+0]=t.x*sc; Q[p*4+1]=t.y*sc; Q[p*4+2]=t.z*sc; Q[p*4+3]=t.w*sc;
    }
  }
  float m = -1e30f, l = 0.f;
  float acc[32];
  #pragma unroll
  for (int d=0;d<32;d++) acc[d]=0.f;

  const int j0 = half*256;
  for (int j=j0; j<j0+256; j+=8){
    float d[8];
    #pragma unroll
    for (int u=0;u<8;u++){
      const float4* kp = (const float4*)&base[(size_t)(j+u)*768 + 256 + h*32];
      float dot = 0.f;
      #pragma unroll
      for (int p=0;p<8;p++){
        float4 t = kp[p];
        dot += Q[p*4+0]*t.x + Q[p*4+1]*t.y + Q[p*4+2]*t.z + Q[p*4+3]*t.w;
      }
      d[u] = dot;
    }
    float mn = m;
    #pragma unroll
    for (int u=0;u<8;u++) mn = fmaxf(mn, d[u]);
    float corr = __expf(m - mn);
    float p[8]; float ps = 0.f;
    #pragma unroll
    for (int u=0;u<8;u++){ p[u] = __expf(d[u]-mn); ps += p[u]; }
    l = l*corr + ps;
    #pragma unroll
    for (int dd=0;dd<32;dd++) acc[dd] *= corr;
    #pragma unroll
    for (int u=0;u<8;u++){
      const float4* vp = (const float4*)&base[(size_t)(j+u)*768 + 512 + h*32];
      float pu = p[u];
      #pragma unroll
      for (int pp=0;pp<8;pp++){
        float4 t = vp[pp];
        acc[pp*4+0] += pu*t.x; acc[pp*4+1] += pu*t.y;
        acc[pp*4+2] += pu*t.z; acc[pp*4+3] += pu*t.w;
      }
    }
    m = mn;
  }
  if (half == 1){
    mrg[lq][0] = m; mrg[lq][1] = 1.f;   // placeholder index 1 reused below
    mrg[lq][1] = l;
    #pragma unroll
    for (int d=0;d<31;d++) mrg[lq][2+d] = acc[d];
  }
  __syncthreads();
  // acc[31] passed via a second LDS pass to keep row width 33 (m,l,acc0..30)
  __shared__ float mrg2[128];
  if (half == 1) mrg2[lq] = acc[31];
  __syncthreads();
  if (half == 0){
    float mu = mrg[lq][0], lu = mrg[lq][1];
    float mn = fmaxf(m, mu);
    float cl = __expf(m - mn), cu = __expf(mu - mn);
    l = l*cl + lu*cu;
    #pragma unroll
    for (int d=0;d<31;d++) acc[d] = acc[d]*cl + mrg[lq][2+d]*cu;
    acc[31] = acc[31]*cl + mrg2[lq]*cu;
    m = mn;
    if (qc >= 4){   // block-uniform target self-attend
      const float4* kp = (const float4*)&base[(size_t)q*768 + 256 + h*32];
      float d0 = 0.f;
      #pragma unroll
      for (int p=0;p<8;p++){
        float4 t = kp[p];
        d0 += Q[p*4+0]*t.x + Q[p*4+1]*t.y + Q[p*4+2]*t.z + Q[p*4+3]*t.w;
      }
      float mn2 = fmaxf(m, d0);
      float corr = __expf(m - mn2);
      float p0 = __expf(d0 - mn2);
      l = l*corr + p0;
      const float4* vp = (const float4*)&base[(size_t)q*768 + 512 + h*32];
      #pragma unroll
      for (int p=0;p<8;p++){
        float4 t = vp[p];
        acc[p*4+0] = acc[p*4+0]*corr + p0*t.x;
        acc[p*4+1] = acc[p*4+1]*corr + p0*t.y;
        acc[p*4+2] = acc[p*4+2]*corr + p0*t.z;
        acc[p*4+3] = acc[p*4+3]*corr + p0*t.w;
      }
    }
    float inv = 1.f/l;
    float* op = o + ((size_t)b*1024 + q)*256 + h*32;
    #pragma unroll
    for (int p=0;p<8;p++){
      float4 t;
      t.x=acc[p*4+0]*inv; t.y=acc[p*4+1]*inv; t.z=acc[p*4+2]*inv; t.w=acc[p*4+3]*inv;
      *(float4*)&op[p*4] = t;
    }
  }
}

// ---------------------------------------------------------------- launch
extern "C" void kernel_launch(void* const* d_in, const int* in_sizes, int n_in,
                              void* d_out, int out_size, void* d_ws, size_t ws_size,
                              hipStream_t stream)
{
  (void)in_sizes; (void)n_in; (void)out_size;
  const float* xc   = (const float*)d_in[0];
  const float* yc   = (const float*)d_in[1];
  const float* xt   = (const float*)d_in[2];
  const float* eW1  = (const float*)d_in[3];
  const float* eb1  = (const float*)d_in[4];
  const float* eW2  = (const float*)d_in[5];
  const float* eb2  = (const float*)d_in[6];
  const float* Wqkv = (const float*)d_in[7];
  const float* bqkv = (const float*)d_in[8];
  const float* Wo   = (const float*)d_in[9];
  const float* bo   = (const float*)d_in[10];
  const float* ln1g = (const float*)d_in[11];
  const float* ln1b = (const float*)d_in[12];
  const float* ln2g = (const float*)d_in[13];
  const float* ln2b = (const float*)d_in[14];
  const float* Wff1 = (const float*)d_in[15];
  const float* bff1 = (const float*)d_in[16];
  const float* Wff2 = (const float*)d_in[17];
  const float* bff2 = (const float*)d_in[18];

  float* zf = (float*)d_out;            // residual stream [8][1024][256] f32
  char* ws = (char*)d_ws;
  float* hb      = (float*)(ws);                        // 8 MB
  float* scratch = (float*)(ws + (size_t)8*1024*1024);  // qkv / ffh

  const bool hugews = (ws_size == 0) || (ws_size >= (size_t)40*1024*1024);
  const bool bigws  = hugews || (ws_size >= (size_t)33*1024*1024);

  encoder_kernel<<<8192, 256, 0, stream>>>(xc, yc, xt, eW1, eb1, eW2, eb2, zf);

  for (int l=0; l<6; l++){
    const float* Wq = Wqkv + (size_t)l*256*768;
    const float* Wl = Wo   + (size_t)l*256*256;
    const float* W1 = Wff1 + (size_t)l*256*1024;
    const float* W2 = Wff2 + (size_t)l*1024*256;

    ln_fast<<<8192, 256, 0, stream>>>(zf, ln1g+l*256, ln1b+l*256, hb);
    if (bigws){
      gemm_big<0><<<dim3(6,64), 256, 0, stream>>>(hb, Wq, bqkv+l*768,
                                                  nullptr, scratch, 768, 256);
      attn_v3<<<dim3(8,8,8), 256, 0, stream>>>(scratch, hb);
    } else {
      for (int c=0; c<4; c++){
        float* hrows = hb + (size_t)c*2048*256;
        gemm_big<0><<<dim3(6,16), 256, 0, stream>>>(hrows, Wq, bqkv+l*768,
                                                    nullptr, scratch, 768, 256);
        attn_v3<<<dim3(8,8,2), 256, 0, stream>>>(scratch, hrows);
      }
    }
    gemm_mid<2><<<dim3(2,128), 256, 0, stream>>>(hb, Wl, bo+l*256, zf, zf, 256, 256);

    ln_fast<<<8192, 256, 0, stream>>>(zf, ln2g+l*256, ln2b+l*256, hb);
    if (hugews){
      gemm_big<1><<<dim3(8,64), 256, 0, stream>>>(hb, W1, bff1+l*1024,
                                                  nullptr, scratch, 1024, 256);
      gemm_mid<2><<<dim3(2,128), 256, 0, stream>>>(scratch, W2, bff2+l*256,
                                                   zf, zf, 256, 1024);
    } else if (bigws){
      for (int c=0; c<2; c++){
        float* hrows = hb + (size_t)c*4096*256;
        float* zrows = zf + (size_t)c*4096*256;
        gemm_big<1><<<dim3(8,32), 256, 0, stream>>>(hrows, W1, bff1+l*1024,
                                                    nullptr, scratch, 1024, 256);
        gemm_mid<2><<<dim3(2,64), 256, 0, stream>>>(scratch, W2, bff2+l*256,
                                                    zrows, zrows, 256, 1024);
      }
    } else {
      for (int c=0; c<4; c++){
        float* hrows = hb + (size_t)c*2048*256;
        float* zrows = zf + (size_t)c*2048*256;
        gemm_big<1><<<dim3(8,16), 256, 0, stream>>>(hrows, W1, bff1+l*1024,
                                                    nullptr, scratch, 1024, 256);
        gemm_mid<2><<<dim3(2,32), 256, 0, stream>>>(scratch, W2, bff2+l*256,
                                                    zrows, zrows, 256, 1024);
      }
    }
  }
}